// Round 1
// baseline (506.718 us; speedup 1.0000x reference)
//
#include <hip/hip_runtime.h>

// Problem constants (from reference): N=524288 rows, IND(K)=128, outd(N)=256, num_grid=255
#define M_TOTAL   524288
#define KDIM      128
#define NCOL      256
#define ROWTILES  (M_TOTAL / 16)   // 32768 tiles of 16 rows
#define GRID_BLOCKS 2048

typedef _Float16 half8  __attribute__((ext_vector_type(8)));
typedef float    floatx4 __attribute__((ext_vector_type(4)));

// LDS logits: 16 rows x 256 cols, stride 257 floats to break bank conflicts
#define LSTRIDE 257

__global__ __launch_bounds__(256)
void density_kernel(const float* __restrict__ t,
                    const float* __restrict__ x,
                    const float* __restrict__ w,     // [128][256] row-major
                    const float* __restrict__ bias,  // [256]
                    float* __restrict__ out)
{
    __shared__ float lds_logits[16 * LSTRIDE];

    const int tid  = threadIdx.x;
    const int wave = tid >> 6;        // 0..3, owns cols [wave*64, wave*64+64)
    const int lane = tid & 63;
    const int n    = lane & 15;       // col-in-16tile (B/C) == row-in-16tile (A)
    const int q    = lane >> 4;       // quad: k-chunk selector / C-row group

    // ---- Load B fragments once per block: fp16(W) for this wave's 64 cols.
    // B layout for mfma_f32_16x16x32_f16: lane supplies B[k = q*8+j][n = lane&15]
    const int colbase = wave * 64;
    half8 bfrag[4][4];   // [coltile][kstep]
    #pragma unroll
    for (int ct = 0; ct < 4; ++ct) {
        const int col = colbase + ct * 16 + n;
        #pragma unroll
        for (int ks = 0; ks < 4; ++ks) {
            const int k0 = ks * 32 + q * 8;
            half8 b;
            #pragma unroll
            for (int j = 0; j < 8; ++j)
                b[j] = (_Float16)w[(k0 + j) * NCOL + col];
            bfrag[ct][ks] = b;
        }
    }
    // bias per coltile (same for all rows -> same for all 4 acc regs)
    float biasv[4];
    #pragma unroll
    for (int ct = 0; ct < 4; ++ct)
        biasv[ct] = bias[colbase + ct * 16 + n];

    for (int tile = blockIdx.x; tile < ROWTILES; tile += gridDim.x) {
        // ---- Load this lane's A rows from global (fp32), 8 floats per kstep.
        // A layout: lane supplies A[m = lane&15][k = q*8+j] (+ ks*32)
        const float* arow = x + (size_t)(tile * 16 + n) * KDIM;
        floatx4 av[4][2];
        #pragma unroll
        for (int ks = 0; ks < 4; ++ks) {
            const floatx4* p = (const floatx4*)(arow + ks * 32 + q * 8);
            av[ks][0] = p[0];
            av[ks][1] = p[1];
        }

        floatx4 acc[4];
        #pragma unroll
        for (int ct = 0; ct < 4; ++ct)
            acc[ct] = (floatx4){biasv[ct], biasv[ct], biasv[ct], biasv[ct]};

        // ---- 2-pass fp16 split MFMA: C = (A_hi + A_lo) @ fp16(B)
        #pragma unroll
        for (int ks = 0; ks < 4; ++ks) {
            half8 ahi, alo;
            const float* af = (const float*)&av[ks][0];
            #pragma unroll
            for (int j = 0; j < 8; ++j) {
                float a = af[j];
                _Float16 h = (_Float16)a;
                ahi[j] = h;
                alo[j] = (_Float16)(a - (float)h);
            }
            #pragma unroll
            for (int ct = 0; ct < 4; ++ct) {
                acc[ct] = __builtin_amdgcn_mfma_f32_16x16x32_f16(ahi, bfrag[ct][ks], acc[ct], 0, 0, 0);
                acc[ct] = __builtin_amdgcn_mfma_f32_16x16x32_f16(alo, bfrag[ct][ks], acc[ct], 0, 0, 0);
            }
        }

        // ---- Stage logits to LDS. C/D layout: row = q*4 + reg, col = lane&15
        #pragma unroll
        for (int ct = 0; ct < 4; ++ct) {
            #pragma unroll
            for (int r = 0; r < 4; ++r)
                lds_logits[(q * 4 + r) * LSTRIDE + colbase + ct * 16 + n] = acc[ct][r];
        }
        __syncthreads();

        // ---- Softmax stats + gather/interp: 16 threads per row
        {
            const int r   = tid >> 4;   // row 0..15
            const int sub = tid & 15;
            const float* lrow = &lds_logits[r * LSTRIDE];

            float m = -1e30f;
            #pragma unroll
            for (int i = 0; i < 16; ++i)
                m = fmaxf(m, lrow[sub + 16 * i]);
            #pragma unroll
            for (int off = 1; off < 16; off <<= 1)
                m = fmaxf(m, __shfl_xor(m, off));

            float s = 0.0f;
            #pragma unroll
            for (int i = 0; i < 16; ++i)
                s += __expf(lrow[sub + 16 * i] - m);
            #pragma unroll
            for (int off = 1; off < 16; off <<= 1)
                s += __shfl_xor(s, off);

            if (sub == 0) {
                const int row = tile * 16 + r;
                const float tv = t[row];
                const float tg = tv * 255.0f;          // t * num_grid
                const float U  = ceilf(tg);
                const float inter = 1.0f - (U - tg);
                float L = U - 1.0f;
                if (L < 0.0f) L = 0.0f;
                const int Li = (int)L;
                const int Ui = (int)U;
                const float inv_s = 1.0f / s;
                const float pl = __expf(lrow[Li] - m) * inv_s;
                const float pu = __expf(lrow[Ui] - m) * inv_s;
                out[row] = pl + (pu - pl) * inter;
            }
        }
        __syncthreads();   // protect LDS before next tile overwrites
    }
}

extern "C" void kernel_launch(void* const* d_in, const int* in_sizes, int n_in,
                              void* d_out, int out_size, void* d_ws, size_t ws_size,
                              hipStream_t stream) {
    const float* t    = (const float*)d_in[0];
    const float* x    = (const float*)d_in[1];
    const float* wgt  = (const float*)d_in[2];
    const float* bias = (const float*)d_in[3];
    float* out = (float*)d_out;

    density_kernel<<<GRID_BLOCKS, 256, 0, stream>>>(t, x, wgt, bias, out);
}

// Round 2
// 486.350 us; speedup vs baseline: 1.0419x; 1.0419x over previous
//
#include <hip/hip_runtime.h>

// N=524288 rows, K=128, outd=256 cols, num_grid=255
#define M_TOTAL     524288
#define KDIM        128
#define NCOL        256
#define NTILES      (M_TOTAL / 16)     // 32768 tiles of 16 rows
#define GRID_BLOCKS 2048

typedef _Float16 half8   __attribute__((ext_vector_type(8)));
typedef float    floatx4 __attribute__((ext_vector_type(4)));

// DPP prefix-sum within each 16-lane row: after shr 1,2,4,8 lane (15 mod 16)
// holds the sum of all 16 lanes. VALU-pipe, no DS traffic.
template <int CTRL>
__device__ __forceinline__ float dpp_add_step(float x) {
    int xi = __builtin_bit_cast(int, x);
    int sh = __builtin_amdgcn_update_dpp(0, xi, CTRL, 0xF, 0xF, true);
    return x + __builtin_bit_cast(float, sh);
}
__device__ __forceinline__ float row16_sum(float x) {
    x = dpp_add_step<0x111>(x);  // row_shr:1
    x = dpp_add_step<0x112>(x);  // row_shr:2
    x = dpp_add_step<0x114>(x);  // row_shr:4
    x = dpp_add_step<0x118>(x);  // row_shr:8
    return x;                    // lane n==15 has the total
}

__global__ __launch_bounds__(256, 3)
void density_kernel(const float* __restrict__ t,
                    const float* __restrict__ x,
                    const float* __restrict__ w,     // [128][256] row-major
                    const float* __restrict__ bias,  // [256]
                    float* __restrict__ out)
{
    // double-buffered per-wave partials: [parity][row-in-tile][wave] = (s, num)
    __shared__ alignas(16) float2 part[2][16][4];

    const int tid  = threadIdx.x;
    const int wave = tid >> 6;        // 0..3, owns cols [wave*64, wave*64+64)
    const int lane = tid & 63;
    const int n    = lane & 15;       // col-in-16 (B/C) == row-in-16 (A)
    const int q    = lane >> 4;       // quad selector
    const int colbase = wave * 64;

    // ---- issue first A-tile loads ASAP (overlap with B-fragment prep)
    {
        const float* arow = x + (size_t)(blockIdx.x * 16 + n) * KDIM;
        // av declared below; loads issued in first loop iteration structure:
    }

    floatx4 av[4][2];
    {
        const float* arow = x + (size_t)(blockIdx.x * 16 + n) * KDIM;
        #pragma unroll
        for (int ks = 0; ks < 4; ++ks) {
            const floatx4* p4 = (const floatx4*)(arow + ks * 32 + q * 8);
            av[ks][0] = p4[0];
            av[ks][1] = p4[1];
        }
    }

    // ---- B fragments in VGPRs for the whole kernel (fp16(W), this wave's 64 cols)
    // B layout for mfma_f32_16x16x32_f16: lane supplies B[k = q*8+j][n]
    half8 bfrag[4][4];   // [coltile][kstep]
    float biasv[4], colf[4];
    #pragma unroll
    for (int ct = 0; ct < 4; ++ct) {
        const int col = colbase + ct * 16 + n;
        #pragma unroll
        for (int ks = 0; ks < 4; ++ks) {
            const int k0 = ks * 32 + q * 8;
            half8 b;
            #pragma unroll
            for (int j = 0; j < 8; ++j)
                b[j] = (_Float16)w[(k0 + j) * NCOL + col];
            bfrag[ct][ks] = b;
        }
        biasv[ct] = bias[col];
        colf[ct]  = (float)col;
    }

    int p = 0;
    for (int tile = blockIdx.x; tile < NTILES; tile += GRID_BLOCKS) {
        // t for this lane's 4 rows (rows q*4 .. q*4+3), 16B-aligned vector load
        const floatx4 tv = *(const floatx4*)(t + tile * 16 + q * 4);

        // ---- convert current A: 2-pass fp16 split (hi + residual)
        half8 ahi[4], alo[4];
        #pragma unroll
        for (int ks = 0; ks < 4; ++ks) {
            const float* af = (const float*)&av[ks][0];
            half8 hi, lo;
            #pragma unroll
            for (int j = 0; j < 8; ++j) {
                float a = af[j];
                _Float16 h = (_Float16)a;
                hi[j] = h;
                lo[j] = (_Float16)(a - (float)h);
            }
            ahi[ks] = hi;
            alo[ks] = lo;
        }

        // ---- av registers are dead now: prefetch next tile into them
        {
            const int ntile = tile + GRID_BLOCKS;
            if (ntile < NTILES) {
                const float* arow = x + (size_t)(ntile * 16 + n) * KDIM;
                #pragma unroll
                for (int ks = 0; ks < 4; ++ks) {
                    const floatx4* p4 = (const floatx4*)(arow + ks * 32 + q * 8);
                    av[ks][0] = p4[0];
                    av[ks][1] = p4[1];
                }
            }
        }

        // ---- MFMA: C = (A_hi + A_lo) @ fp16(W), bias folded into acc init
        floatx4 acc[4];
        #pragma unroll
        for (int ct = 0; ct < 4; ++ct)
            acc[ct] = (floatx4){biasv[ct], biasv[ct], biasv[ct], biasv[ct]};
        #pragma unroll
        for (int ks = 0; ks < 4; ++ks) {
            #pragma unroll
            for (int ct = 0; ct < 4; ++ct) {
                acc[ct] = __builtin_amdgcn_mfma_f32_16x16x32_f16(ahi[ks], bfrag[ct][ks], acc[ct], 0, 0, 0);
                acc[ct] = __builtin_amdgcn_mfma_f32_16x16x32_f16(alo[ks], bfrag[ct][ks], acc[ct], 0, 0, 0);
            }
        }

        // ---- fused epilogue: no max-sub (|logit| << 88), hat-function interp
        // out[row] = sum_c e_c * max(0, 1-|c - t*255|) / sum_c e_c
        floatx4 tg;
        #pragma unroll
        for (int r = 0; r < 4; ++r) tg[r] = tv[r] * 255.0f;

        float s4[4]   = {0.f, 0.f, 0.f, 0.f};
        float num4[4] = {0.f, 0.f, 0.f, 0.f};
        #pragma unroll
        for (int ct = 0; ct < 4; ++ct) {
            #pragma unroll
            for (int r = 0; r < 4; ++r) {
                float e = __expf(acc[ct][r]);
                s4[r] += e;
                float d = colf[ct] - tg[r];
                float wt = fmaxf(0.0f, 1.0f - fabsf(d));
                num4[r] = fmaf(e, wt, num4[r]);
            }
        }

        // ---- reduce across the 16-lane n-group (DPP, VALU pipe)
        #pragma unroll
        for (int r = 0; r < 4; ++r) {
            s4[r]   = row16_sum(s4[r]);
            num4[r] = row16_sum(num4[r]);
        }

        // holder lane writes this wave's per-row partials (tiny LDS)
        if (n == 15) {
            #pragma unroll
            for (int r = 0; r < 4; ++r)
                part[p][q * 4 + r][wave] = make_float2(s4[r], num4[r]);
        }
        __syncthreads();

        // ---- combine 4 wave-partials per row, store 16 outputs
        if (tid < 16) {
            const float4* pr = (const float4*)&part[p][tid][0];
            float4 a = pr[0], b = pr[1];
            float s  = a.x + a.z + b.x + b.z;
            float nm = a.y + a.w + b.y + b.w;
            out[tile * 16 + tid] = nm / s;
        }
        p ^= 1;   // double-buffer: next tile's writes don't race this combine
    }
}

extern "C" void kernel_launch(void* const* d_in, const int* in_sizes, int n_in,
                              void* d_out, int out_size, void* d_ws, size_t ws_size,
                              hipStream_t stream) {
    const float* t    = (const float*)d_in[0];
    const float* x    = (const float*)d_in[1];
    const float* wgt  = (const float*)d_in[2];
    const float* bias = (const float*)d_in[3];
    float* out = (float*)d_out;

    density_kernel<<<GRID_BLOCKS, 256, 0, stream>>>(t, x, wgt, bias, out);
}

// Round 3
// 450.606 us; speedup vs baseline: 1.1245x; 1.0793x over previous
//
#include <hip/hip_runtime.h>

// N=524288 rows, K=128, outd=256 cols, num_grid=255
#define M_TOTAL     524288
#define KDIM        128
#define NCOL        256
#define NITER       (M_TOTAL / 32)     // 16384 iterations of 32 rows (2 subtiles of 16)
#define GRID_BLOCKS 2048               // -> 8 iterations per block
#define LOG2E       1.44269504088896340736f

typedef _Float16 half8   __attribute__((ext_vector_type(8)));
typedef float    floatx4 __attribute__((ext_vector_type(4)));

// DPP prefix-sum within each 16-lane group (VALU pipe, no DS traffic).
// After shr 1,2,4,8 lane (15 mod 16) holds the 16-lane total.
template <int CTRL>
__device__ __forceinline__ float dpp_add_step(float x) {
    int xi = __builtin_bit_cast(int, x);
    int sh = __builtin_amdgcn_update_dpp(0, xi, CTRL, 0xF, 0xF, true);
    return x + __builtin_bit_cast(float, sh);
}
__device__ __forceinline__ float row16_sum(float x) {
    x = dpp_add_step<0x111>(x);  // row_shr:1
    x = dpp_add_step<0x112>(x);  // row_shr:2
    x = dpp_add_step<0x114>(x);  // row_shr:4
    x = dpp_add_step<0x118>(x);  // row_shr:8
    return x;
}

// waves_per_eu(2,2): pin the allocator to a 256-VGPR budget so bfrag (64 regs)
// stays resident. R2 evidence: default heuristic went to 84 VGPR -> remat/spill
// (WRITE_SIZE 9.5MB, VALUBusy 2x structural estimate).
__global__ __attribute__((amdgpu_flat_work_group_size(256, 256), amdgpu_waves_per_eu(2, 2)))
void density_kernel(const float* __restrict__ t,
                    const float* __restrict__ x,
                    const float* __restrict__ w,     // [128][256] row-major
                    const float* __restrict__ bias,  // [256]
                    float* __restrict__ out)
{
    // per-wave partials: [parity][subtile][row-in-16][wave] = (denom, numer)
    __shared__ alignas(16) float2 part[2][2][16][4];

    const int tid  = threadIdx.x;
    const int wave = tid >> 6;        // 0..3, owns cols [wave*64, wave*64+64)
    const int lane = tid & 63;
    const int n    = lane & 15;       // col-in-16 (B/C) == row-in-16 (A)
    const int q    = lane >> 4;       // quad selector
    const int colbase = wave * 64;

    // ---- B fragments resident in VGPRs for the whole kernel.
    // fp16(W * log2e): exp(logit) == exp2(logit') with logits' = A@(W*log2e) + b*log2e.
    // B layout for mfma_f32_16x16x32_f16: lane supplies B[k = q*8+j][n]
    half8 bfrag[4][4];   // [coltile][kstep]
    float biasv[4], colf[4];
    #pragma unroll
    for (int ct = 0; ct < 4; ++ct) {
        const int col = colbase + ct * 16 + n;
        #pragma unroll
        for (int ks = 0; ks < 4; ++ks) {
            const int k0 = ks * 32 + q * 8;
            half8 b;
            #pragma unroll
            for (int j = 0; j < 8; ++j)
                b[j] = (_Float16)(w[(k0 + j) * NCOL + col] * LOG2E);
            bfrag[ct][ks] = b;
        }
        biasv[ct] = bias[col] * LOG2E;
        colf[ct]  = (float)col;
    }

    int p = 0;
    for (int it = blockIdx.x; it < NITER; it += GRID_BLOCKS) {
        const int row0 = it * 32;

        // ---- issue all global loads for both subtiles up front
        const float* arowA = x + (size_t)(row0 + n) * KDIM;
        const float* arowB = arowA + 16 * KDIM;
        floatx4 avA[4][2], avB[4][2];
        #pragma unroll
        for (int ks = 0; ks < 4; ++ks) {
            const floatx4* pA = (const floatx4*)(arowA + ks * 32 + q * 8);
            avA[ks][0] = pA[0];
            avA[ks][1] = pA[1];
        }
        #pragma unroll
        for (int ks = 0; ks < 4; ++ks) {
            const floatx4* pB = (const floatx4*)(arowB + ks * 32 + q * 8);
            avB[ks][0] = pB[0];
            avB[ks][1] = pB[1];
        }
        const floatx4 tvA = *(const floatx4*)(t + row0 + q * 4);
        const floatx4 tvB = *(const floatx4*)(t + row0 + 16 + q * 4);

        // ---- subtile A: fp16 2-pass split, MFMA
        floatx4 accA[4], accB[4];
        #pragma unroll
        for (int ct = 0; ct < 4; ++ct) {
            accA[ct] = (floatx4){biasv[ct], biasv[ct], biasv[ct], biasv[ct]};
            accB[ct] = accA[ct];
        }
        {
            half8 ahi[4], alo[4];
            #pragma unroll
            for (int ks = 0; ks < 4; ++ks) {
                const float* af = (const float*)&avA[ks][0];
                #pragma unroll
                for (int j = 0; j < 8; ++j) {
                    float a = af[j];
                    _Float16 h = (_Float16)a;
                    ahi[ks][j] = h;
                    alo[ks][j] = (_Float16)(a - (float)h);
                }
            }
            #pragma unroll
            for (int ks = 0; ks < 4; ++ks) {
                #pragma unroll
                for (int ct = 0; ct < 4; ++ct) {
                    accA[ct] = __builtin_amdgcn_mfma_f32_16x16x32_f16(ahi[ks], bfrag[ct][ks], accA[ct], 0, 0, 0);
                    accA[ct] = __builtin_amdgcn_mfma_f32_16x16x32_f16(alo[ks], bfrag[ct][ks], accA[ct], 0, 0, 0);
                }
            }
        }
        // ---- subtile B
        {
            half8 ahi[4], alo[4];
            #pragma unroll
            for (int ks = 0; ks < 4; ++ks) {
                const float* af = (const float*)&avB[ks][0];
                #pragma unroll
                for (int j = 0; j < 8; ++j) {
                    float a = af[j];
                    _Float16 h = (_Float16)a;
                    ahi[ks][j] = h;
                    alo[ks][j] = (_Float16)(a - (float)h);
                }
            }
            #pragma unroll
            for (int ks = 0; ks < 4; ++ks) {
                #pragma unroll
                for (int ct = 0; ct < 4; ++ct) {
                    accB[ct] = __builtin_amdgcn_mfma_f32_16x16x32_f16(ahi[ks], bfrag[ct][ks], accB[ct], 0, 0, 0);
                    accB[ct] = __builtin_amdgcn_mfma_f32_16x16x32_f16(alo[ks], bfrag[ct][ks], accB[ct], 0, 0, 0);
                }
            }
        }

        // ---- fused epilogues (hat-function interp, no max-sub: |logit| << 126)
        // out[row] = sum_c 2^z_c * max(0, 1-|c - t*255|) / sum_c 2^z_c
        float sA[4] = {0,0,0,0}, nmA[4] = {0,0,0,0};
        float sB[4] = {0,0,0,0}, nmB[4] = {0,0,0,0};
        #pragma unroll
        for (int ct = 0; ct < 4; ++ct) {
            #pragma unroll
            for (int r = 0; r < 4; ++r) {
                float eA = __builtin_amdgcn_exp2f(accA[ct][r]);
                float eB = __builtin_amdgcn_exp2f(accB[ct][r]);
                sA[r] += eA;
                sB[r] += eB;
                float wA = fmaxf(0.0f, 1.0f - fabsf(colf[ct] - tvA[r] * 255.0f));
                float wB = fmaxf(0.0f, 1.0f - fabsf(colf[ct] - tvB[r] * 255.0f));
                nmA[r] = fmaf(eA, wA, nmA[r]);
                nmB[r] = fmaf(eB, wB, nmB[r]);
            }
        }

        // ---- 16-lane reductions on the VALU pipe
        #pragma unroll
        for (int r = 0; r < 4; ++r) {
            sA[r]  = row16_sum(sA[r]);
            nmA[r] = row16_sum(nmA[r]);
            sB[r]  = row16_sum(sB[r]);
            nmB[r] = row16_sum(nmB[r]);
        }

        if (n == 15) {
            #pragma unroll
            for (int r = 0; r < 4; ++r) {
                part[p][0][q * 4 + r][wave] = make_float2(sA[r], nmA[r]);
                part[p][1][q * 4 + r][wave] = make_float2(sB[r], nmB[r]);
            }
        }
        __syncthreads();

        // ---- combine 4 wave-partials per row, store 32 outputs
        if (tid < 32) {
            const int st = tid >> 4, r = tid & 15;
            const float4* pr = (const float4*)&part[p][st][r][0];
            float4 a = pr[0], b = pr[1];
            float s  = a.x + a.z + b.x + b.z;
            float nm = a.y + a.w + b.y + b.w;
            out[row0 + tid] = nm / s;
        }
        p ^= 1;  // double-buffer: next iteration's writes can't race this combine
    }
}

extern "C" void kernel_launch(void* const* d_in, const int* in_sizes, int n_in,
                              void* d_out, int out_size, void* d_ws, size_t ws_size,
                              hipStream_t stream) {
    const float* t    = (const float*)d_in[0];
    const float* x    = (const float*)d_in[1];
    const float* wgt  = (const float*)d_in[2];
    const float* bias = (const float*)d_in[3];
    float* out = (float*)d_out;

    density_kernel<<<GRID_BLOCKS, 256, 0, stream>>>(t, x, wgt, bias, out);
}